// Round 12
// baseline (160.261 us; speedup 1.0000x reference)
//
#include <hip/hip_runtime.h>
#include <math.h>

// Density-Aware Chamfer Loss, B=4, N=8192, fp32 3D points.
//
// Round-12: keep r11's MFMA partial (45us, MfmaUtil 14%, absmax 0.0) verbatim;
// collapse merge+count+loss into ONE kernel at 256 blocks (1/CU, co-resident)
// with the r10-validated threadfence/spin barrier. Tail analysis across r5-r11
// shows ~15-25us per dispatch boundary dominates the non-partial time.
//
// dacl_final phases:
//   A1: 1 thread/query, strict-< scan of 64 group-min slots (coalesced rows;
//       ties -> lowest group = global-first-min given ascending groups)
//   A2: 4 lanes/query x 4 passes: each lane rescans a 32-target quarter of the
//       winning group with EXACT distances, packed u32 key
//       (bits(d) & ~0x7F) | idx7 -> u32 min = first-min tie-break (jnp.argmin)
//   count: atomicAdd cnt[idx]
//   barrier: threadfence + agent-scope arrive spin (256 blocks co-resident)
//   B: loss from d unpacked from key (<=2^-17 rel trunc) + cnt, wave-reduce,
//      atomicAdd out[b] / (2N)
//
// ws: [slot 64grp x 2BN f32 (16.8MB)][cnt 2BN int][arrive int]
// Dispatches: partial(+zero cnt,arrive) -> final(+zero out).   (2 total)

#define NPTS   8192
#define BLK    256
#define QPB    128                  // queries per block (4 waves x 32)
#define TPS    2048                 // targets per slice
#define TILES  (TPS / 32)           // 64 MFMA tiles per slice
#define NSLICE (NPTS / TPS)         // 4
#define QCH    (NPTS / QPB)         // 64
#define GRP    128                  // targets per slot group
#define NGRP   (NPTS / GRP)         // 64

typedef __attribute__((ext_vector_type(8)))  short short8;
typedef __attribute__((ext_vector_type(16))) float float16v;

__device__ inline void bsplit(float x, unsigned short& h, unsigned short& l) {
    const unsigned int u = __float_as_uint(x);
    const unsigned short hh = (unsigned short)(u >> 16);   // truncated bf16 hi
    const float lf = x - __uint_as_float((unsigned int)hh << 16);
    h = hh;
    l = (unsigned short)(__float_as_uint(lf) >> 16);       // bf16 lo
}

__global__ __launch_bounds__(BLK) void dacl_partial(
    const float* __restrict__ gts, const float* __restrict__ preds,
    float* __restrict__ slot, int* __restrict__ cnt, int* __restrict__ arrive,
    int B, int N)
{
    const int bz  = blockIdx.z;      // dir*B + b
    const int dir = bz / B;
    const int b   = bz - dir * B;
    const int total = 2 * B * N;

    // fold cnt/arrive zeroing in (first read by dacl_final -> boundary orders)
    if (blockIdx.y == 0) {
        const int per = total / (QCH * 2 * B);             // 128
        int* p = cnt + (blockIdx.x + QCH * bz) * per;
        for (int k = threadIdx.x; k < per; k += BLK) p[k] = 0;
        if (blockIdx.x == 0 && bz == 0 && threadIdx.x == 0) *arrive = 0;
    }

    const float* __restrict__ q = (dir == 0 ? gts : preds) + (size_t)b * N * 3;
    const float* __restrict__ t = (dir == 0 ? preds : gts) + (size_t)b * N * 3;

    __shared__ short8 frag[TILES * 64];                    // 64KB A-frags

    // stage+pack A-frags: 2048 targets, 8 per thread.  MFMA K=13 layout:
    // k0-2 thi.(-2qhi)  k3-5 thi.(-2qlo)  k6-8 tlo.(-2qhi)
    // k9 |t|^2hi.1  k10 |t|^2lo.1  k11 1.|q|^2hi  k12 1.|q|^2lo
    const int sbase = blockIdx.y * TPS;
    for (int rep = 0; rep < TPS / BLK; ++rep) {
        const int tgt = rep * BLK + threadIdx.x;
        const int j   = sbase + tgt;
        const float tx = t[3 * j], ty = t[3 * j + 1], tz = t[3 * j + 2];
        const float t2 = fmaf(tx, tx, fmaf(ty, ty, tz * tz));
        unsigned short hx, lx, hy, ly, hz, lz, h2, l2;
        bsplit(tx, hx, lx); bsplit(ty, hy, ly); bsplit(tz, hz, lz); bsplit(t2, h2, l2);
        union { short8 v; unsigned short s[8]; } k0, k1;
        k0.s[0]=hx; k0.s[1]=hy; k0.s[2]=hz; k0.s[3]=hx; k0.s[4]=hy; k0.s[5]=hz; k0.s[6]=lx; k0.s[7]=ly;
        k1.s[0]=lz; k1.s[1]=h2; k1.s[2]=l2; k1.s[3]=0x3F80; k1.s[4]=0x3F80; k1.s[5]=0; k1.s[6]=0; k1.s[7]=0;
        const int tile = tgt >> 5, row = tgt & 31;
        frag[tile * 64 + row]      = k0.v;                 // k-half 0 (lanes 0-31)
        frag[tile * 64 + 32 + row] = k1.v;                 // k-half 1 (lanes 32-63)
    }

    // B-frag: each wave owns 32 queries; lane&31 = query col (HW-verified
    // col=lane&31, m74/m101), lane>>5 = k-half
    const int lane = threadIdx.x & 63;
    const int wave = threadIdx.x >> 6;
    const int qi   = blockIdx.x * QPB + wave * 32 + (lane & 31);
    const float qx = q[3 * qi], qy = q[3 * qi + 1], qz = q[3 * qi + 2];
    const float q2 = fmaf(qx, qx, fmaf(qy, qy, qz * qz));
    unsigned short shx, slx, shy, sly, shz, slz, h2q, l2q;
    bsplit(-2.0f * qx, shx, slx); bsplit(-2.0f * qy, shy, sly);
    bsplit(-2.0f * qz, shz, slz); bsplit(q2, h2q, l2q);
    union { short8 v; unsigned short s[8]; } bu;
    if ((lane >> 5) == 0) {
        bu.s[0]=shx; bu.s[1]=shy; bu.s[2]=shz; bu.s[3]=slx; bu.s[4]=sly; bu.s[5]=slz; bu.s[6]=shx; bu.s[7]=shy;
    } else {
        bu.s[0]=shz; bu.s[1]=0x3F80; bu.s[2]=0x3F80; bu.s[3]=h2q; bu.s[4]=l2q; bu.s[5]=0; bu.s[6]=0; bu.s[7]=0;
    }
    const short8 bfrag = bu.v;

    __syncthreads();

    const float16v zz = {0.f,0.f,0.f,0.f, 0.f,0.f,0.f,0.f,
                         0.f,0.f,0.f,0.f, 0.f,0.f,0.f,0.f};
    const size_t gq = (size_t)bz * N + qi;
    float gmin = 3.402823466e38f;

    // hot loop: 1 ds_read_b128 + 1 mfma + 9-op min3 tree per 1024 pairs.
    // group-min is invariant to the C/D row permutation.
    #pragma unroll 2
    for (int tile = 0; tile < TILES; ++tile) {
        const short8 av = frag[tile * 64 + lane];
        float16v acc = __builtin_amdgcn_mfma_f32_32x32x16_bf16(av, bfrag, zz, 0, 0, 0);
        const float t0 = fminf(fminf(acc[0],  acc[1]),  acc[2]);
        const float t1 = fminf(fminf(acc[3],  acc[4]),  acc[5]);
        const float t2 = fminf(fminf(acc[6],  acc[7]),  acc[8]);
        const float t3 = fminf(fminf(acc[9],  acc[10]), acc[11]);
        const float t4 = fminf(fminf(acc[12], acc[13]), acc[14]);
        const float u0 = fminf(fminf(t0, t1), acc[15]);
        const float u1 = fminf(fminf(t2, t3), t4);
        gmin = fminf(gmin, fminf(u0, u1));
        if ((tile & 3) == 3) {                             // close a 128-target group
            const float o = fminf(gmin, __shfl_xor(gmin, 32, 64));  // both row-halves
            if (lane < 32)
                slot[(size_t)(blockIdx.y * (TILES / 4) + (tile >> 2)) * total + gq] = o;
            gmin = 3.402823466e38f;
        }
    }
}

// merge + count + loss fused; 256 blocks = 1/CU, co-resident (r10-validated)
__global__ __launch_bounds__(BLK) void dacl_final(
    const float* __restrict__ gts, const float* __restrict__ preds,
    const float* __restrict__ slot, int* __restrict__ cnt,
    int* __restrict__ arrive, float* __restrict__ out, int out_size,
    int B, int N)
{
    const int tid = threadIdx.x;
    const int g   = blockIdx.x * BLK + tid;                // query id
    const int total = 2 * B * N;
    const int bz  = (blockIdx.x * BLK) / N;                // block-uniform (N%BLK==0)
    const int dir = bz / B;
    const int b   = bz - dir * B;
    const float* __restrict__ q = (dir == 0 ? gts : preds) + (size_t)b * N * 3;
    const float* __restrict__ t = (dir == 0 ? preds : gts) + (size_t)b * N * 3;

    __shared__ int          sgr[BLK];
    __shared__ unsigned int sres[BLK];

    if (blockIdx.x == 0 && tid < out_size) out[tid] = 0.0f;

    // A1: strict-< scan of 64 group mins; ties -> lowest group
    {
        float m = slot[g];
        int gr = 0;
        #pragma unroll 8
        for (int s = 1; s < NGRP; ++s) {
            const float v = slot[(size_t)s * total + g];   // coalesced row
            if (v < m) { m = v; gr = s; }
        }
        sgr[tid] = gr;
    }
    __syncthreads();

    // A2: 4 lanes per query, 4 passes; each lane rescans a 32-target quarter
    // of the winning group with EXACT distances; packed u32 first-min key.
    const int sub = tid & 3;
    for (int pass = 0; pass < 4; ++pass) {
        const int ql  = pass * 64 + (tid >> 2);            // local query 0..255
        const int qiq = (blockIdx.x * BLK + ql) - bz * N;  // in-batch query idx
        const int grq = sgr[ql];
        const float qx = q[3 * qiq], qy = q[3 * qiq + 1], qz = q[3 * qiq + 2];
        const float4* __restrict__ tb4 =
            (const float4*)(t + (size_t)grq * GRP * 3) + sub * 24;  // 32 targets
        unsigned int best = 0xFFFFFFFFu;
        #pragma unroll
        for (int c = 0; c < 2; ++c) {                      // 16 targets per chunk
            float f[48];
            #pragma unroll
            for (int j2 = 0; j2 < 12; ++j2) {
                const float4 v = tb4[c * 12 + j2];
                f[4*j2] = v.x; f[4*j2+1] = v.y; f[4*j2+2] = v.z; f[4*j2+3] = v.w;
            }
            #pragma unroll
            for (int tt = 0; tt < 16; ++tt) {
                const float dx = qx - f[3*tt], dy = qy - f[3*tt+1], dz = qz - f[3*tt+2];
                const float d  = fmaf(dx, dx, fmaf(dy, dy, dz * dz));  // exact >= 0
                const unsigned int pk = (__float_as_uint(d) & 0xFFFFFF80u)
                                      | (unsigned int)(sub * 32 + c * 16 + tt);
                best = min(best, pk);                      // ties -> lowest idx7
            }
        }
        best = min(best, (unsigned int)__shfl_xor((int)best, 1, 64));
        best = min(best, (unsigned int)__shfl_xor((int)best, 2, 64));
        if (sub == 0) sres[ql] = best;
    }
    __syncthreads();

    const unsigned int key = sres[tid];
    const int idxg = sgr[tid] * GRP + (int)(key & 127u);   // global NN index
    atomicAdd(&cnt[bz * N + idxg], 1);

    // grid barrier: 256 blocks, 1/CU co-resident -> spin is deadlock-free
    __threadfence();
    __syncthreads();
    if (tid == 0) {
        __hip_atomic_fetch_add(arrive, 1, __ATOMIC_ACQ_REL, __HIP_MEMORY_SCOPE_AGENT);
        while (__hip_atomic_load(arrive, __ATOMIC_ACQUIRE, __HIP_MEMORY_SCOPE_AGENT)
               < (int)gridDim.x)
            __builtin_amdgcn_s_sleep(8);
    }
    __syncthreads();

    // B: loss. d from the key's high bits (<=2^-17 rel truncation of exact d).
    const float d = __uint_as_float(key & 0xFFFFFF80u);
    const int   c = __hip_atomic_load(&cnt[bz * N + idxg], __ATOMIC_RELAXED,
                                      __HIP_MEMORY_SCOPE_AGENT);
    float sv = 1.0f - expf(-d) / ((float)c + 1e-6f);       // count^1, frac = 1
    for (int off = 32; off > 0; off >>= 1) sv += __shfl_down(sv, off, 64);
    if ((tid & 63) == 0)
        atomicAdd(&out[b], sv / (2.0f * (float)N));        // (mean1+mean2)/2
}

extern "C" void kernel_launch(void* const* d_in, const int* in_sizes, int n_in,
                              void* d_out, int out_size, void* d_ws, size_t ws_size,
                              hipStream_t stream)
{
    const float* gts   = (const float*)d_in[0];
    const float* preds = (const float*)d_in[1];

    const int N = NPTS;
    const int B = in_sizes[0] / (N * 3);                   // = 4

    const size_t nTot = (size_t)2 * B * N;                 // 65536 queries
    float* slot   = (float*)d_ws;                          // NGRP x nTot (16.8MB)
    int*   cnt    = (int*)((char*)d_ws + (size_t)NGRP * nTot * sizeof(float));
    int*   arrive = cnt + nTot;

    dim3 gA(QCH, NSLICE, 2 * B);                           // 64 x 4 x 8 = 2048 blocks
    dacl_partial<<<gA, BLK, 0, stream>>>(gts, preds, slot, cnt, arrive, B, N);

    dacl_final<<<(int)(nTot / BLK), BLK, 0, stream>>>(     // 256 blocks
        gts, preds, slot, cnt, arrive, (float*)d_out, out_size, B, N);
}